// Round 2
// baseline (470.956 us; speedup 1.0000x reference)
//
#include <hip/hip_runtime.h>

// ---------------- problem constants ----------------
#define N_ANCH 221184      // H*W*A = 128*192*9
#define HW     24576       // H*W
#define Wd     192
#define Hd     128
#define AA     9
#define TOPN   6000
#define POSTN  300
#define CAND_CAP 8192
#define NWORDS 94          // ceil(6016/64) words of suppression bits

// anchor widths/heights (== ws2/hs2 of the reference, exact small ints)
// ratio 0.5: 23x12 -> w {184,368,736}, h {96,192,384}
// ratio 1.0: 16x16 -> w {128,256,512}, h {128,256,512}
// ratio 2.0: 11x22 -> w { 88,176,352}, h {176,352,704}
__device__ const float c_aw[9] = {184.f,368.f,736.f,128.f,256.f,512.f, 88.f,176.f,352.f};
__device__ const float c_ah[9] = { 96.f,192.f,384.f,128.f,256.f,512.f,176.f,352.f,704.f};
// note: ctr_x = 16*w + 8 and ctr_y = 16*h + 8 exactly, for every anchor a.

// ---------------- kernels ----------------

__global__ __launch_bounds__(1024) void init_kernel(unsigned int* hist, unsigned int* state) {
    int t = threadIdx.x;
    hist[t] = 0u;                    // 4 rounds x 256 buckets
    if (t == 0) { state[0] = 0u; state[1] = TOPN; state[2] = 0u; state[3] = 0u; }
}

// thread t maps to (a = t/HW, cell = t%HW) so reads of scores/deltas are coalesced.
// boxes/keys are stored in this same j-layout; the reference anchor index
// (cell*9 + a) is only materialized in the sort key for tie-breaking.
__global__ __launch_bounds__(256) void decode_kernel(const float* __restrict__ scores,
                                                     const float* __restrict__ deltas,
                                                     const float* __restrict__ iminfo,
                                                     float4* __restrict__ boxesj,
                                                     unsigned int* __restrict__ keys,
                                                     unsigned int* __restrict__ hist3) {
    __shared__ unsigned int lh[256];
    lh[threadIdx.x] = 0u;
    __syncthreads();

    int t = blockIdx.x * 256 + threadIdx.x;
    if (t < N_ANCH) {
        int a = t / HW;
        int cell = t - a * HW;
        int h = cell / Wd;
        int w = cell - h * Wd;

        float score = scores[(AA + a) * HW + cell];
        const float* db = deltas + (size_t)(4 * a) * HW + cell;
        float dx = db[0];
        float dy = db[HW];
        float dw = db[2 * HW];
        float dh = db[3 * HW];
        dw = fminf(fmaxf(dw, -10.f), 10.f);
        dh = fminf(fmaxf(dh, -10.f), 10.f);

        float ww = c_aw[a], hh = c_ah[a];
        float cx = 16.f * (float)w + 8.f;   // exact
        float cy = 16.f * (float)h + 8.f;   // exact

        // match numpy rounding: no FMA contraction
        float pcx = __fadd_rn(__fmul_rn(dx, ww), cx);
        float pcy = __fadd_rn(__fmul_rn(dy, hh), cy);
        float pw  = __fmul_rn(expf(dw), ww);
        float ph  = __fmul_rn(expf(dh), hh);
        float hpw = __fmul_rn(0.5f, pw);
        float hph = __fmul_rn(0.5f, ph);
        float x1 = __fsub_rn(pcx, hpw);
        float x2 = __fadd_rn(pcx, hpw);
        float y1 = __fsub_rn(pcy, hph);
        float y2 = __fadd_rn(pcy, hph);

        float info0 = iminfo[0], info1 = iminfo[1], info2 = iminfo[2];
        float xmax = __fsub_rn(info1, 1.f);
        float ymax = __fsub_rn(info0, 1.f);
        x1 = fminf(fmaxf(x1, 0.f), xmax);
        x2 = fminf(fmaxf(x2, 0.f), xmax);
        y1 = fminf(fmaxf(y1, 0.f), ymax);
        y2 = fminf(fmaxf(y2, 0.f), ymax);

        float msz = __fmul_rn(16.f, info2);
        bool valid = (__fadd_rn(__fsub_rn(x2, x1), 1.f) >= msz) &&
                     (__fadd_rn(__fsub_rn(y2, y1), 1.f) >= msz);

        unsigned int sb = __float_as_uint(score);
        // flip to ordered-uint; invalid -> key of -inf (0x007FFFFF)
        unsigned int key = valid ? ((sb & 0x80000000u) ? ~sb : (sb | 0x80000000u))
                                 : 0x007FFFFFu;
        boxesj[t] = make_float4(x1, y1, x2, y2);
        keys[t] = key;
        atomicAdd(&lh[key >> 24], 1u);
    }
    __syncthreads();
    atomicAdd(&hist3[threadIdx.x], lh[threadIdx.x]);
}

__global__ __launch_bounds__(256) void hist_kernel(const unsigned int* __restrict__ keys,
                                                   const unsigned int* __restrict__ state,
                                                   unsigned int* __restrict__ hist,
                                                   int shift, unsigned int himask) {
    __shared__ unsigned int lh[256];
    lh[threadIdx.x] = 0u;
    __syncthreads();
    unsigned int pref = state[0];
    int t = blockIdx.x * 256 + threadIdx.x;
    if (t < N_ANCH) {
        unsigned int k = keys[t];
        if ((k & himask) == (pref & himask))
            atomicAdd(&lh[(k >> shift) & 0xFFu], 1u);
    }
    __syncthreads();
    atomicAdd(&hist[threadIdx.x], lh[threadIdx.x]);
}

__global__ __launch_bounds__(256) void select_kernel(const unsigned int* __restrict__ hist,
                                                     unsigned int* __restrict__ state,
                                                     int shift) {
    __shared__ unsigned int s[256];
    int t = threadIdx.x;
    s[t] = hist[t];
    unsigned int rank = state[1];   // read BEFORE any write (single block, sync below)
    __syncthreads();
    // inclusive suffix sum: s[t] = count of elements with bucket >= t
    for (int d = 1; d < 256; d <<= 1) {
        unsigned int v = (t + d < 256) ? s[t + d] : 0u;
        __syncthreads();
        s[t] += v;
        __syncthreads();
    }
    unsigned int ge = s[t];
    unsigned int gt = (t < 255) ? s[t + 1] : 0u;
    if (ge >= rank && gt < rank) {
        state[0] |= ((unsigned int)t) << shift;
        state[1] = rank - gt;
    }
}

__global__ __launch_bounds__(256) void compact_kernel(const unsigned int* __restrict__ keys,
                                                      unsigned int* __restrict__ state,
                                                      unsigned long long* __restrict__ cand) {
    int t = blockIdx.x * 256 + threadIdx.x;
    if (t >= N_ANCH) return;
    unsigned int k = keys[t];
    unsigned int T = state[0];
    if (k >= T) {
        unsigned int pos = atomicAdd(&state[2], 1u);
        if (pos < CAND_CAP) {
            int a = t / HW;
            int cell = t - a * HW;
            unsigned int aidx = (unsigned int)(cell * 9 + a);  // reference anchor index
            cand[pos] = ((unsigned long long)k << 32) | (unsigned long long)(~aidx);
        }
    }
}

// single block: bitonic sort 8192 u64 keys descending -> top-6000 in score order
// (ties by ascending anchor index, matching lax.top_k). Then gather boxes and
// build the validity bitmask.
__global__ __launch_bounds__(1024) void sort_kernel(const unsigned long long* __restrict__ cand,
                                                    const unsigned int* __restrict__ state,
                                                    const float4* __restrict__ boxesj,
                                                    float4* __restrict__ tb,
                                                    unsigned long long* __restrict__ validmask) {
    __shared__ unsigned long long s[CAND_CAP];
    int tid = threadIdx.x;
    unsigned int cc = state[2];
    if (cc > CAND_CAP) cc = CAND_CAP;
    for (int i = tid; i < CAND_CAP; i += 1024)
        s[i] = (i < (int)cc) ? cand[i] : 0ull;
    __syncthreads();

    for (int k = 2; k <= CAND_CAP; k <<= 1) {
        for (int j = k >> 1; j > 0; j >>= 1) {
            for (int t = tid; t < CAND_CAP; t += 1024) {
                int l = t ^ j;
                if (l > t) {
                    unsigned long long a = s[t], b = s[l];
                    bool desc = ((t & k) == 0);
                    if (desc ? (a < b) : (a > b)) { s[t] = b; s[l] = a; }
                }
            }
            __syncthreads();
        }
    }

    // epilogue: gather top-6000 boxes, emit valid bitmask (6016 bits / 94 words)
    for (int i = tid; i < 6016; i += 1024) {
        bool valid = false;
        if (i < TOPN) {
            unsigned long long kv = s[i];
            float4 box = make_float4(0.f, 0.f, 0.f, 0.f);
            if (kv != 0ull) {
                unsigned int hi   = (unsigned int)(kv >> 32);
                unsigned int aidx = ~((unsigned int)kv);
                int a = (int)(aidx % 9u);
                int cell = (int)(aidx / 9u);
                box = boxesj[(size_t)a * HW + cell];
                valid = (hi != 0x007FFFFFu);
            }
            tb[i] = box;
        }
        unsigned long long m = __ballot(valid);
        if ((tid & 63) == 0) validmask[i >> 6] = m;
    }
}

// suppression bit-matrix: mat[row][wordcol] bit c = (IoU(row, 64*wordcol+c) > 0.7)
__global__ __launch_bounds__(64) void nms_matrix_kernel(const float4* __restrict__ tb,
                                                        unsigned long long* __restrict__ mat) {
    __shared__ float4 cb[64];
    int t = threadIdx.x;
    int c0 = blockIdx.x * 64;
    int col = c0 + t;
    cb[t] = (col < TOPN) ? tb[col] : make_float4(0.f, 0.f, 0.f, 0.f);
    __syncthreads();
    int row = blockIdx.y * 64 + t;
    if (row >= TOPN) return;
    float4 rb = tb[row];
    float rA = (rb.z - rb.x) * (rb.w - rb.y);
    unsigned long long mask = 0ull;
    for (int c = 0; c < 64; ++c) {
        if (c0 + c >= TOPN) break;
        float4 b = cb[c];
        float lx = fmaxf(rb.x, b.x), ly = fmaxf(rb.y, b.y);
        float rx = fminf(rb.z, b.z), ry = fminf(rb.w, b.w);
        float iw = fmaxf(rx - lx, 0.f), ih = fmaxf(ry - ly, 0.f);
        float inter = iw * ih;
        float bA = (b.z - b.x) * (b.w - b.y);
        float iou = inter / ((rA + bA) - inter);
        if (iou > 0.7f) mask |= (1ull << c);   // NaN compares false, as in numpy
    }
    mat[(size_t)row * NWORDS + blockIdx.x] = mask;
}

// single-wave greedy scan. remv words 0..93 distributed: lane l holds word l (r0)
// and word 64+l (r1, lanes 0..29). Decision bit broadcast via shfl. Early-exit
// at 300 kept (only the first 300 kept rows are emitted by the reference).
__global__ __launch_bounds__(64) void nms_scan_kernel(const unsigned long long* __restrict__ mat,
                                                      const unsigned long long* __restrict__ validmask,
                                                      const float4* __restrict__ tb,
                                                      float* __restrict__ out) {
    int lane = threadIdx.x;
    unsigned long long r0 = ~validmask[lane];
    unsigned long long r1 = (lane < NWORDS - 64) ? ~validmask[64 + lane] : ~0ull;
    __shared__ int kept[POSTN];
    int cnt = 0;
    for (int w = 0; w < NWORDS && cnt < POSTN; ++w) {
        unsigned long long word = __shfl((w < 64) ? r0 : r1, w & 63);
        int base = w << 6;
        for (int b = 0; b < 64; ++b) {
            int i = base + b;
            if (i >= TOPN) break;
            if ((word >> b) & 1ull) continue;
            if (lane == 0) kept[cnt] = i;
            ++cnt;
            const unsigned long long* row = mat + (size_t)i * NWORDS;
            unsigned long long m0 = row[lane];
            unsigned long long m1 = (lane < NWORDS - 64) ? row[64 + lane] : 0ull;
            r0 |= m0;
            r1 |= m1;
            if (cnt >= POSTN) break;
            word = __shfl((w < 64) ? r0 : r1, w & 63);
        }
    }
    __syncthreads();
    for (int r = lane; r < POSTN; r += 64) {
        float4 b = make_float4(0.f, 0.f, 0.f, 0.f);
        if (r < cnt) b = tb[kept[r]];
        float* o = out + r * 5;
        o[0] = 0.f; o[1] = b.x; o[2] = b.y; o[3] = b.z; o[4] = b.w;
    }
}

// ---------------- host launcher ----------------
extern "C" void kernel_launch(void* const* d_in, const int* in_sizes, int n_in,
                              void* d_out, int out_size, void* d_ws, size_t ws_size,
                              hipStream_t stream) {
    const float* scores = (const float*)d_in[0];
    const float* deltas = (const float*)d_in[1];
    const float* iminfo = (const float*)d_in[2];
    float* out = (float*)d_out;

    char* ws = (char*)d_ws;
    // workspace layout (16B-aligned chunks), total ~9.1 MB
    float4*             boxesj = (float4*)(ws + 0);                       // N*16      = 3538944
    unsigned int*       keys   = (unsigned int*)(ws + 3538944);           // N*4       = 884736
    unsigned int*       hist   = (unsigned int*)(ws + 4423680);           // 4*256*4   = 4096
    unsigned int*       state  = (unsigned int*)(ws + 4427776);           // 64
    unsigned long long* cand   = (unsigned long long*)(ws + 4427840);     // 8192*8    = 65536
    float4*             tb     = (float4*)(ws + 4493376);                 // 6016*16   = 96256
    unsigned long long* vmask  = (unsigned long long*)(ws + 4589632);     // 94*8 -> 768
    unsigned long long* mat    = (unsigned long long*)(ws + 4590400);     // 6000*94*8 = 4512000

    const int NB = N_ANCH / 256;   // 864 exactly

    init_kernel<<<1, 1024, 0, stream>>>(hist, state);
    decode_kernel<<<NB, 256, 0, stream>>>(scores, deltas, iminfo, boxesj, keys, hist + 3 * 256);
    select_kernel<<<1, 256, 0, stream>>>(hist + 3 * 256, state, 24);
    hist_kernel<<<NB, 256, 0, stream>>>(keys, state, hist + 2 * 256, 16, 0xFF000000u);
    select_kernel<<<1, 256, 0, stream>>>(hist + 2 * 256, state, 16);
    hist_kernel<<<NB, 256, 0, stream>>>(keys, state, hist + 1 * 256, 8, 0xFFFF0000u);
    select_kernel<<<1, 256, 0, stream>>>(hist + 1 * 256, state, 8);
    hist_kernel<<<NB, 256, 0, stream>>>(keys, state, hist + 0 * 256, 0, 0xFFFFFF00u);
    select_kernel<<<1, 256, 0, stream>>>(hist + 0 * 256, state, 0);
    compact_kernel<<<NB, 256, 0, stream>>>(keys, state, cand);
    sort_kernel<<<1, 1024, 0, stream>>>(cand, state, boxesj, tb, vmask);
    nms_matrix_kernel<<<dim3(NWORDS, NWORDS), 64, 0, stream>>>(tb, mat);
    nms_scan_kernel<<<1, 64, 0, stream>>>(mat, vmask, tb, out);
}

// Round 3
// 433.069 us; speedup vs baseline: 1.0875x; 1.0875x over previous
//
#include <hip/hip_runtime.h>

// ---------------- problem constants ----------------
#define N_ANCH 221184      // H*W*A = 128*192*9
#define HW     24576       // H*W
#define Wd     192
#define AA     9
#define TOPN   6000
#define POSTN  300
#define CAND_CAP 8192
#define RJ     2048        // rank kernel j-chunk
#define NWORDS 94          // ceil(6016/64) words of suppression bits

// anchor widths/heights (== ws2/hs2 of the reference, exact small ints)
// ratio 0.5: 23x12 -> w {184,368,736}, h { 96,192,384}
// ratio 1.0: 16x16 -> w {128,256,512}, h {128,256,512}
// ratio 2.0: 11x22 -> w { 88,176,352}, h {176,352,704}
__device__ const float c_aw[9] = {184.f,368.f,736.f,128.f,256.f,512.f, 88.f,176.f,352.f};
__device__ const float c_ah[9] = { 96.f,192.f,384.f,128.f,256.f,512.f,176.f,352.f,704.f};

// ---------------- init: zero hist/state/cand/tb/vmask + rank ----------------
#define Z1_F4 10420   // (4096 + 64 + 65536 + 96256 + 768) / 16
#define Z2_F4 2048    // 32768 / 16  (rank aliases head of mat)
__global__ __launch_bounds__(256) void init_kernel(float4* z1, float4* z2) {
    int t = blockIdx.x * 256 + threadIdx.x;
    if (t < Z1_F4) {
        if (t == 256) ((int4*)z1)[t] = make_int4(0, TOPN, 0, 0);  // state = {prefix,rank,cc,0}
        else z1[t] = make_float4(0.f, 0.f, 0.f, 0.f);
    } else if (t < Z1_F4 + Z2_F4) {
        z2[t - Z1_F4] = make_float4(0.f, 0.f, 0.f, 0.f);
    }
}

// thread t maps to (a = t/HW, cell = t%HW) so reads of scores/deltas are coalesced.
// boxes/keys are stored in this j-layout; the reference anchor index (cell*9+a)
// is only materialized in the sort key for tie-breaking.
__global__ __launch_bounds__(256) void decode_kernel(const float* __restrict__ scores,
                                                     const float* __restrict__ deltas,
                                                     const float* __restrict__ iminfo,
                                                     float4* __restrict__ boxesj,
                                                     unsigned int* __restrict__ keys,
                                                     unsigned int* __restrict__ hist_r1) {
    __shared__ unsigned int lh[256];
    lh[threadIdx.x] = 0u;
    __syncthreads();

    int t = blockIdx.x * 256 + threadIdx.x;
    {
        int a = t / HW;
        int cell = t - a * HW;
        int h = cell / Wd;
        int w = cell - h * Wd;

        float score = scores[(AA + a) * HW + cell];
        const float* db = deltas + (size_t)(4 * a) * HW + cell;
        float dx = db[0];
        float dy = db[HW];
        float dw = db[2 * HW];
        float dh = db[3 * HW];
        dw = fminf(fmaxf(dw, -10.f), 10.f);
        dh = fminf(fmaxf(dh, -10.f), 10.f);

        float ww = c_aw[a], hh = c_ah[a];
        float cx = 16.f * (float)w + 8.f;   // exact
        float cy = 16.f * (float)h + 8.f;   // exact

        // match numpy rounding: no FMA contraction
        float pcx = __fadd_rn(__fmul_rn(dx, ww), cx);
        float pcy = __fadd_rn(__fmul_rn(dy, hh), cy);
        float pw  = __fmul_rn(expf(dw), ww);
        float ph  = __fmul_rn(expf(dh), hh);
        float hpw = __fmul_rn(0.5f, pw);
        float hph = __fmul_rn(0.5f, ph);
        float x1 = __fsub_rn(pcx, hpw);
        float x2 = __fadd_rn(pcx, hpw);
        float y1 = __fsub_rn(pcy, hph);
        float y2 = __fadd_rn(pcy, hph);

        float info0 = iminfo[0], info1 = iminfo[1], info2 = iminfo[2];
        float xmax = __fsub_rn(info1, 1.f);
        float ymax = __fsub_rn(info0, 1.f);
        x1 = fminf(fmaxf(x1, 0.f), xmax);
        x2 = fminf(fmaxf(x2, 0.f), xmax);
        y1 = fminf(fmaxf(y1, 0.f), ymax);
        y2 = fminf(fmaxf(y2, 0.f), ymax);

        float msz = __fmul_rn(16.f, info2);
        bool valid = (__fadd_rn(__fsub_rn(x2, x1), 1.f) >= msz) &&
                     (__fadd_rn(__fsub_rn(y2, y1), 1.f) >= msz);

        unsigned int sb = __float_as_uint(score);
        // flip to ordered-uint; invalid -> key of -inf (0x007FFFFF)
        unsigned int key = valid ? ((sb & 0x80000000u) ? ~sb : (sb | 0x80000000u))
                                 : 0x007FFFFFu;
        boxesj[t] = make_float4(x1, y1, x2, y2);
        keys[t] = key;
        atomicAdd(&lh[key >> 24], 1u);
    }
    __syncthreads();
    atomicAdd(&hist_r1[threadIdx.x], lh[threadIdx.x]);
}

__global__ __launch_bounds__(256) void hist_kernel(const unsigned int* __restrict__ keys,
                                                   const unsigned int* __restrict__ state,
                                                   unsigned int* __restrict__ hist,
                                                   int shift, unsigned int himask) {
    __shared__ unsigned int lh[256];
    lh[threadIdx.x] = 0u;
    __syncthreads();
    unsigned int pref = state[0];
    int t = blockIdx.x * 256 + threadIdx.x;
    {
        unsigned int k = keys[t];
        if ((k & himask) == (pref & himask))
            atomicAdd(&lh[(k >> shift) & 0xFFu], 1u);
    }
    __syncthreads();
    atomicAdd(&hist[threadIdx.x], lh[threadIdx.x]);
}

__global__ __launch_bounds__(256) void select_kernel(const unsigned int* __restrict__ hist,
                                                     unsigned int* __restrict__ state,
                                                     int shift) {
    __shared__ unsigned int s[256];
    int t = threadIdx.x;
    s[t] = hist[t];
    unsigned int rank = state[1];   // read BEFORE any write (single block, sync below)
    __syncthreads();
    // inclusive suffix sum: s[t] = count of elements with bucket >= t
    for (int d = 1; d < 256; d <<= 1) {
        unsigned int v = (t + d < 256) ? s[t + d] : 0u;
        __syncthreads();
        s[t] += v;
        __syncthreads();
    }
    unsigned int ge = s[t];
    unsigned int gt = (t < 255) ? s[t + 1] : 0u;
    if (ge >= rank && gt < rank) {
        state[0] |= ((unsigned int)t) << shift;
        state[1] = rank - gt;
    }
}

// take all keys >= T (T has low 16 bits zero; boundary bin fully included,
// cc ~ 6000 + a few hundred, well under CAND_CAP for uniform scores)
__global__ __launch_bounds__(256) void compact_kernel(const unsigned int* __restrict__ keys,
                                                      unsigned int* __restrict__ state,
                                                      unsigned long long* __restrict__ cand) {
    int t = blockIdx.x * 256 + threadIdx.x;
    unsigned int k = keys[t];
    unsigned int T = state[0];
    if (k >= T) {
        unsigned int pos = atomicAdd(&state[2], 1u);
        if (pos < CAND_CAP) {
            int a = t / HW;
            int cell = t - a * HW;
            unsigned int aidx = (unsigned int)(cell * 9 + a);  // reference anchor index
            cand[pos] = ((unsigned long long)k << 32) | (unsigned long long)(~aidx);
        }
    }
}

// exact rank by counting: rank[i] = #{j : key_j > key_i}. Keys are distinct
// (index in low bits) so ranks are a permutation == sorted position
// (score desc, index asc — exactly lax.top_k order). Zero-padded entries skip.
__global__ __launch_bounds__(256) void rank_kernel(const unsigned long long* __restrict__ cand,
                                                   unsigned int* __restrict__ rank) {
    __shared__ unsigned long long s[RJ];
    const unsigned long long* src = cand + (size_t)blockIdx.y * RJ;
    for (int j = threadIdx.x; j < RJ; j += 256) s[j] = src[j];
    int i = blockIdx.x * 256 + threadIdx.x;
    unsigned long long k = cand[i];
    __syncthreads();
    unsigned int cnt = 0;
    #pragma unroll 16
    for (int j = 0; j < RJ; ++j) cnt += (s[j] > k) ? 1u : 0u;   // LDS broadcast reads
    if (k != 0ull && cnt != 0u) atomicAdd(&rank[i], cnt);
}

// place boxes at their sorted position; set validity bit.
__global__ __launch_bounds__(256) void scatter_kernel(const unsigned long long* __restrict__ cand,
                                                      const unsigned int* __restrict__ rank,
                                                      const float4* __restrict__ boxesj,
                                                      float4* __restrict__ tb,
                                                      unsigned long long* __restrict__ vmask) {
    int i = blockIdx.x * 256 + threadIdx.x;
    unsigned long long k = cand[i];
    if (k == 0ull) return;
    unsigned int r = rank[i];
    if (r >= TOPN) return;
    unsigned int hi = (unsigned int)(k >> 32);
    unsigned int aidx = ~((unsigned int)k);
    int a = (int)(aidx % 9u);
    int cell = (int)(aidx / 9u);
    tb[r] = boxesj[(size_t)a * HW + cell];
    if (hi != 0x007FFFFFu) atomicOr(&vmask[r >> 6], 1ull << (r & 63));
}

// suppression bit-matrix, upper-triangle word-blocks only (bits for j<=i are
// never re-read by the scan, so lower-triangle words may stay uninitialized).
__global__ __launch_bounds__(64) void nms_matrix_kernel(const float4* __restrict__ tb,
                                                        unsigned long long* __restrict__ mat) {
    if (blockIdx.x < blockIdx.y) return;   // word-col block entirely left of row block
    __shared__ float4 cb[64];
    int t = threadIdx.x;
    int c0 = blockIdx.x * 64;
    int col = c0 + t;
    cb[t] = (col < TOPN) ? tb[col] : make_float4(0.f, 0.f, 0.f, 0.f);
    __syncthreads();
    int row = blockIdx.y * 64 + t;
    if (row >= TOPN) return;
    float4 rb = tb[row];
    float rA = (rb.z - rb.x) * (rb.w - rb.y);
    unsigned long long mask = 0ull;
    for (int c = 0; c < 64; ++c) {
        if (c0 + c >= TOPN) break;
        float4 b = cb[c];
        float lx = fmaxf(rb.x, b.x), ly = fmaxf(rb.y, b.y);
        float rx = fminf(rb.z, b.z), ry = fminf(rb.w, b.w);
        float iw = fmaxf(rx - lx, 0.f), ih = fmaxf(ry - ly, 0.f);
        float inter = iw * ih;
        float bA = (b.z - b.x) * (b.w - b.y);
        float iou = inter / ((rA + bA) - inter);
        if (iou > 0.7f) mask |= (1ull << c);   // NaN compares false, as in numpy
    }
    mat[(size_t)row * NWORDS + blockIdx.x] = mask;
}

// find first alive index >= from; removal words distributed one per lane
// (r0: words 0..63, r1: words 64..93). Returns INT_MAX if none.
__device__ __forceinline__ int next_alive(unsigned long long r0, unsigned long long r1,
                                          int from, int lane) {
    int best = 0x7FFFFFFF;
    {
        int base = lane << 6;
        int d = from - base;
        unsigned long long excl = (d <= 0) ? 0ull : (d >= 64 ? ~0ull : ((1ull << d) - 1ull));
        unsigned long long avail = ~(r0 | excl);
        if (avail) best = base + (__ffsll((unsigned long long)avail) - 1);
    }
    {
        int base = (64 + lane) << 6;
        int d = from - base;
        unsigned long long excl = (d <= 0) ? 0ull : (d >= 64 ? ~0ull : ((1ull << d) - 1ull));
        unsigned long long avail = ~(r1 | excl);
        if (avail) { int c = base + (__ffsll((unsigned long long)avail) - 1); best = min(best, c); }
    }
    #pragma unroll
    for (int d = 32; d; d >>= 1) best = min(best, __shfl_xor(best, d));
    return best;
}

// single-wave greedy scan with depth-1 speculative row prefetch: the load of
// the PREDICTED next row is issued before the current row's mask is consumed,
// so on spec-hit the dependent load has been in flight a full iteration.
__global__ __launch_bounds__(64) void nms_scan_kernel(const unsigned long long* __restrict__ mat,
                                                      const unsigned long long* __restrict__ vmask,
                                                      const float4* __restrict__ tb,
                                                      float* __restrict__ out) {
    int lane = threadIdx.x;
    unsigned long long r0 = ~vmask[lane];
    unsigned long long r1 = (lane < NWORDS - 64) ? ~vmask[64 + lane] : ~0ull;
    __shared__ int kept[POSTN];
    int cnt = 0;

    int cur = next_alive(r0, r1, 0, lane);
    unsigned long long m0 = 0ull, m1 = 0ull;
    if (cur < TOPN) {
        const unsigned long long* row = mat + (size_t)cur * NWORDS;
        m0 = row[lane];
        m1 = (lane < NWORDS - 64) ? row[64 + lane] : 0ull;
    }
    while (cur < TOPN && cnt < POSTN) {
        // speculate the next alive under the PRE-update mask; issue its load now
        int spec = next_alive(r0, r1, cur + 1, lane);
        unsigned long long p0 = 0ull, p1 = 0ull;
        if (spec < TOPN) {
            const unsigned long long* row = mat + (size_t)spec * NWORDS;
            p0 = row[lane];
            p1 = (lane < NWORDS - 64) ? row[64 + lane] : 0ull;
        }
        // commit cur (alive by construction)
        if (lane == 0) kept[cnt] = cur;
        ++cnt;
        r0 |= m0; r1 |= m1;            // waits vmcnt for m-loads only (p still in flight)
        int nxt = next_alive(r0, r1, cur + 1, lane);
        if (nxt == spec) { m0 = p0; m1 = p1; }       // spec hit: row already in flight
        else if (nxt < TOPN) {                        // spec miss: reload (stall)
            const unsigned long long* row = mat + (size_t)nxt * NWORDS;
            m0 = row[lane];
            m1 = (lane < NWORDS - 64) ? row[64 + lane] : 0ull;
        }
        cur = nxt;
    }
    __syncthreads();
    for (int r = lane; r < POSTN; r += 64) {
        float4 b = make_float4(0.f, 0.f, 0.f, 0.f);
        if (r < cnt) b = tb[kept[r]];
        float* o = out + r * 5;
        o[0] = 0.f; o[1] = b.x; o[2] = b.y; o[3] = b.z; o[4] = b.w;
    }
}

// ---------------- host launcher ----------------
extern "C" void kernel_launch(void* const* d_in, const int* in_sizes, int n_in,
                              void* d_out, int out_size, void* d_ws, size_t ws_size,
                              hipStream_t stream) {
    const float* scores = (const float*)d_in[0];
    const float* deltas = (const float*)d_in[1];
    const float* iminfo = (const float*)d_in[2];
    float* out = (float*)d_out;

    char* ws = (char*)d_ws;
    // workspace layout (16B-aligned), total 9,102,400 bytes
    float4*             boxesj = (float4*)(ws + 0);                       // 221184*16 = 3538944
    unsigned int*       keys   = (unsigned int*)(ws + 3538944);           // 221184*4  = 884736
    unsigned int*       hist   = (unsigned int*)(ws + 4423680);           // 2*256*4 used (4096 reserved)
    unsigned int*       state  = (unsigned int*)(ws + 4427776);           // 64
    unsigned long long* cand   = (unsigned long long*)(ws + 4427840);     // 8192*8    = 65536
    float4*             tb     = (float4*)(ws + 4493376);                 // 6016*16   = 96256
    unsigned long long* vmask  = (unsigned long long*)(ws + 4589632);     // 768
    unsigned long long* mat    = (unsigned long long*)(ws + 4590400);     // 6000*94*8 = 4512000
    unsigned int*       rankp  = (unsigned int*)mat;                      // aliases mat head (32KB),
                                                                          // consumed before mat written

    const int NB = N_ANCH / 256;   // 864 exactly

    init_kernel<<<49, 256, 0, stream>>>((float4*)(ws + 4423680), (float4*)mat);
    decode_kernel<<<NB, 256, 0, stream>>>(scores, deltas, iminfo, boxesj, keys, hist + 256);
    select_kernel<<<1, 256, 0, stream>>>(hist + 256, state, 24);
    hist_kernel<<<NB, 256, 0, stream>>>(keys, state, hist, 16, 0xFF000000u);
    select_kernel<<<1, 256, 0, stream>>>(hist, state, 16);
    compact_kernel<<<NB, 256, 0, stream>>>(keys, state, cand);
    rank_kernel<<<dim3(CAND_CAP / 256, CAND_CAP / RJ), 256, 0, stream>>>(cand, rankp);
    scatter_kernel<<<CAND_CAP / 256, 256, 0, stream>>>(cand, rankp, boxesj, tb, vmask);
    nms_matrix_kernel<<<dim3(NWORDS, NWORDS), 64, 0, stream>>>(tb, mat);
    nms_scan_kernel<<<1, 64, 0, stream>>>(mat, vmask, tb, out);
}

// Round 4
// 256.469 us; speedup vs baseline: 1.8363x; 1.6886x over previous
//
#include <hip/hip_runtime.h>

// ---------------- problem constants ----------------
#define N_ANCH 221184      // H*W*A = 128*192*9
#define HW     24576       // H*W
#define Wd     192
#define AA     9
#define TOPN   6000
#define POSTN  300
#define CAND_CAP 8192
#define RJ     2048        // rank kernel j-chunk
#define NWORDS 94          // ceil(6016/64) words of suppression bits

typedef unsigned long long u64;

// anchor widths/heights (== ws2/hs2 of the reference, exact small ints)
// ratio 0.5: 23x12 -> w {184,368,736}, h { 96,192,384}
// ratio 1.0: 16x16 -> w {128,256,512}, h {128,256,512}
// ratio 2.0: 11x22 -> w { 88,176,352}, h {176,352,704}
__device__ const float c_aw[9] = {184.f,368.f,736.f,128.f,256.f,512.f, 88.f,176.f,352.f};
__device__ const float c_ah[9] = { 96.f,192.f,384.f,128.f,256.f,512.f,176.f,352.f,704.f};

// ---------------- init: zero hist/state/cand/tb/vmask + rank ----------------
#define Z1_F4 10420   // (4096 + 64 + 65536 + 96256 + 768) / 16
#define Z2_F4 2048    // 32768 / 16  (rank aliases head of mat)
__global__ __launch_bounds__(256) void init_kernel(float4* z1, float4* z2) {
    int t = blockIdx.x * 256 + threadIdx.x;
    if (t < Z1_F4) {
        if (t == 256) ((int4*)z1)[t] = make_int4(0, TOPN, 0, 0);  // state = {prefix,rank,cc,0}
        else z1[t] = make_float4(0.f, 0.f, 0.f, 0.f);
    } else if (t < Z1_F4 + Z2_F4) {
        z2[t - Z1_F4] = make_float4(0.f, 0.f, 0.f, 0.f);
    }
}

// thread t maps to (a = t/HW, cell = t%HW) so reads of scores/deltas are coalesced.
// boxes/keys are stored in this j-layout; the reference anchor index (cell*9+a)
// is only materialized in the sort key for tie-breaking.
__global__ __launch_bounds__(256) void decode_kernel(const float* __restrict__ scores,
                                                     const float* __restrict__ deltas,
                                                     const float* __restrict__ iminfo,
                                                     float4* __restrict__ boxesj,
                                                     unsigned int* __restrict__ keys,
                                                     unsigned int* __restrict__ hist_r1) {
    __shared__ unsigned int lh[256];
    lh[threadIdx.x] = 0u;
    __syncthreads();

    int t = blockIdx.x * 256 + threadIdx.x;
    {
        int a = t / HW;
        int cell = t - a * HW;
        int h = cell / Wd;
        int w = cell - h * Wd;

        float score = scores[(AA + a) * HW + cell];
        const float* db = deltas + (size_t)(4 * a) * HW + cell;
        float dx = db[0];
        float dy = db[HW];
        float dw = db[2 * HW];
        float dh = db[3 * HW];
        dw = fminf(fmaxf(dw, -10.f), 10.f);
        dh = fminf(fmaxf(dh, -10.f), 10.f);

        float ww = c_aw[a], hh = c_ah[a];
        float cx = 16.f * (float)w + 8.f;   // exact
        float cy = 16.f * (float)h + 8.f;   // exact

        // match numpy rounding: no FMA contraction
        float pcx = __fadd_rn(__fmul_rn(dx, ww), cx);
        float pcy = __fadd_rn(__fmul_rn(dy, hh), cy);
        float pw  = __fmul_rn(expf(dw), ww);
        float ph  = __fmul_rn(expf(dh), hh);
        float hpw = __fmul_rn(0.5f, pw);
        float hph = __fmul_rn(0.5f, ph);
        float x1 = __fsub_rn(pcx, hpw);
        float x2 = __fadd_rn(pcx, hpw);
        float y1 = __fsub_rn(pcy, hph);
        float y2 = __fadd_rn(pcy, hph);

        float info0 = iminfo[0], info1 = iminfo[1], info2 = iminfo[2];
        float xmax = __fsub_rn(info1, 1.f);
        float ymax = __fsub_rn(info0, 1.f);
        x1 = fminf(fmaxf(x1, 0.f), xmax);
        x2 = fminf(fmaxf(x2, 0.f), xmax);
        y1 = fminf(fmaxf(y1, 0.f), ymax);
        y2 = fminf(fmaxf(y2, 0.f), ymax);

        float msz = __fmul_rn(16.f, info2);
        bool valid = (__fadd_rn(__fsub_rn(x2, x1), 1.f) >= msz) &&
                     (__fadd_rn(__fsub_rn(y2, y1), 1.f) >= msz);

        unsigned int sb = __float_as_uint(score);
        // flip to ordered-uint; invalid -> key of -inf (0x007FFFFF)
        unsigned int key = valid ? ((sb & 0x80000000u) ? ~sb : (sb | 0x80000000u))
                                 : 0x007FFFFFu;
        boxesj[t] = make_float4(x1, y1, x2, y2);
        keys[t] = key;
        atomicAdd(&lh[key >> 24], 1u);
    }
    __syncthreads();
    atomicAdd(&hist_r1[threadIdx.x], lh[threadIdx.x]);
}

__global__ __launch_bounds__(256) void hist_kernel(const unsigned int* __restrict__ keys,
                                                   const unsigned int* __restrict__ state,
                                                   unsigned int* __restrict__ hist,
                                                   int shift, unsigned int himask) {
    __shared__ unsigned int lh[256];
    lh[threadIdx.x] = 0u;
    __syncthreads();
    unsigned int pref = state[0];
    int t = blockIdx.x * 256 + threadIdx.x;
    {
        unsigned int k = keys[t];
        if ((k & himask) == (pref & himask))
            atomicAdd(&lh[(k >> shift) & 0xFFu], 1u);
    }
    __syncthreads();
    atomicAdd(&hist[threadIdx.x], lh[threadIdx.x]);
}

__global__ __launch_bounds__(256) void select_kernel(const unsigned int* __restrict__ hist,
                                                     unsigned int* __restrict__ state,
                                                     int shift) {
    __shared__ unsigned int s[256];
    int t = threadIdx.x;
    s[t] = hist[t];
    unsigned int rank = state[1];   // read BEFORE any write (single block, sync below)
    __syncthreads();
    // inclusive suffix sum: s[t] = count of elements with bucket >= t
    for (int d = 1; d < 256; d <<= 1) {
        unsigned int v = (t + d < 256) ? s[t + d] : 0u;
        __syncthreads();
        s[t] += v;
        __syncthreads();
    }
    unsigned int ge = s[t];
    unsigned int gt = (t < 255) ? s[t + 1] : 0u;
    if (ge >= rank && gt < rank) {
        state[0] |= ((unsigned int)t) << shift;
        state[1] = rank - gt;
    }
}

// take all keys >= T (T has low 16 bits zero; boundary bin fully included,
// cc ~ 6000 + a few hundred, well under CAND_CAP for uniform scores)
__global__ __launch_bounds__(256) void compact_kernel(const unsigned int* __restrict__ keys,
                                                      unsigned int* __restrict__ state,
                                                      u64* __restrict__ cand) {
    int t = blockIdx.x * 256 + threadIdx.x;
    unsigned int k = keys[t];
    unsigned int T = state[0];
    if (k >= T) {
        unsigned int pos = atomicAdd(&state[2], 1u);
        if (pos < CAND_CAP) {
            int a = t / HW;
            int cell = t - a * HW;
            unsigned int aidx = (unsigned int)(cell * 9 + a);  // reference anchor index
            cand[pos] = ((u64)k << 32) | (u64)(~aidx);
        }
    }
}

// exact rank by counting: rank[i] = #{j : key_j > key_i}. Keys are distinct
// (index in low bits) so ranks are a permutation == sorted position
// (score desc, index asc — exactly lax.top_k order). Zero-padded entries skip.
__global__ __launch_bounds__(256) void rank_kernel(const u64* __restrict__ cand,
                                                   unsigned int* __restrict__ rank) {
    __shared__ u64 s[RJ];
    const u64* src = cand + (size_t)blockIdx.y * RJ;
    for (int j = threadIdx.x; j < RJ; j += 256) s[j] = src[j];
    int i = blockIdx.x * 256 + threadIdx.x;
    u64 k = cand[i];
    __syncthreads();
    unsigned int cnt = 0;
    #pragma unroll 16
    for (int j = 0; j < RJ; ++j) cnt += (s[j] > k) ? 1u : 0u;   // LDS broadcast reads
    if (k != 0ull && cnt != 0u) atomicAdd(&rank[i], cnt);
}

// place boxes at their sorted position; set validity bit.
__global__ __launch_bounds__(256) void scatter_kernel(const u64* __restrict__ cand,
                                                      const unsigned int* __restrict__ rank,
                                                      const float4* __restrict__ boxesj,
                                                      float4* __restrict__ tb,
                                                      u64* __restrict__ vmask) {
    int i = blockIdx.x * 256 + threadIdx.x;
    u64 k = cand[i];
    if (k == 0ull) return;
    unsigned int r = rank[i];
    if (r >= TOPN) return;
    unsigned int hi = (unsigned int)(k >> 32);
    unsigned int aidx = ~((unsigned int)k);
    int a = (int)(aidx % 9u);
    int cell = (int)(aidx / 9u);
    tb[r] = boxesj[(size_t)a * HW + cell];
    if (hi != 0x007FFFFFu) atomicOr(&vmask[r >> 6], 1ull << (r & 63));
}

// suppression bit-matrix, upper-triangle word-blocks only (bits for j<=i are
// never re-read by the scan, so lower-triangle words may stay uninitialized).
__global__ __launch_bounds__(64) void nms_matrix_kernel(const float4* __restrict__ tb,
                                                        u64* __restrict__ mat) {
    if (blockIdx.x < blockIdx.y) return;   // word-col block entirely left of row block
    __shared__ float4 cb[64];
    int t = threadIdx.x;
    int c0 = blockIdx.x * 64;
    int col = c0 + t;
    cb[t] = (col < TOPN) ? tb[col] : make_float4(0.f, 0.f, 0.f, 0.f);
    __syncthreads();
    int row = blockIdx.y * 64 + t;
    if (row >= TOPN) return;
    float4 rb = tb[row];
    float rA = (rb.z - rb.x) * (rb.w - rb.y);
    u64 mask = 0ull;
    for (int c = 0; c < 64; ++c) {
        if (c0 + c >= TOPN) break;
        float4 b = cb[c];
        float lx = fmaxf(rb.x, b.x), ly = fmaxf(rb.y, b.y);
        float rx = fminf(rb.z, b.z), ry = fminf(rb.w, b.w);
        float iw = fmaxf(rx - lx, 0.f), ih = fmaxf(ry - ly, 0.f);
        float inter = iw * ih;
        float bA = (b.z - b.x) * (b.w - b.y);
        float iou = inter / ((rA + bA) - inter);
        if (iou > 0.7f) mask |= (1ull << c);   // NaN compares false, as in numpy
    }
    mat[(size_t)row * NWORDS + blockIdx.x] = mask;
}

// chunked greedy NMS scan, single wave. Removal words distributed one per lane
// (r0: words 0..63, r1: words 64..93, lane-private). Per 64-box chunk:
//  - lane b preloads the DIAGONAL word mat[c*64+b][c] (off the critical path)
//  - in-chunk greedy loop: pure ALU + one 64-bit shfl per kept box
//  - future-chunk suppression: per kept box, lane w ORs mat[i][w] (w>c);
//    loads batched 8 kept deep so the vmcnt wait amortizes.
__global__ __launch_bounds__(64) void nms_scan_kernel(const u64* __restrict__ mat,
                                                      const u64* __restrict__ vmask,
                                                      const float4* __restrict__ tb,
                                                      float* __restrict__ out) {
    int lane = threadIdx.x;
    u64 r0 = ~vmask[lane];
    u64 r1 = (lane < NWORDS - 64) ? ~vmask[64 + lane] : ~0ull;
    __shared__ int kept[POSTN];
    int cnt = 0;

    for (int c = 0; c < NWORDS && cnt < POSTN; ++c) {
        // issue the diagonal-word load before status is known
        int i0 = c * 64 + lane;
        u64 intra = 0ull;
        if (i0 < TOPN) intra = mat[(size_t)i0 * NWORDS + c];

        u64 stat = (c < 64) ? __shfl(r0, c) : __shfl(r1, c - 64);
        if (stat == ~0ull) continue;   // whole chunk dead

        // in-chunk sequential greedy (wave-uniform, ~1 shfl per kept box)
        u64 removed = stat;
        u64 keptmask = 0ull;
        while (removed != ~0ull && cnt < POSTN) {
            int b = __ffsll((u64)~removed) - 1;
            keptmask |= (1ull << b);
            if (lane == 0) kept[cnt] = c * 64 + b;
            ++cnt;
            removed |= __shfl(intra, b) | (1ull << b);
        }
        if (cnt >= POSTN) break;       // propagation is moot

        // propagate kept rows' suppression to future words, 8 kept per batch
        u64 f0 = 0ull, f1 = 0ull;
        u64 km = keptmask;
        while (km) {
            int bs[8];
            #pragma unroll
            for (int j = 0; j < 8; ++j) {
                bs[j] = km ? (__ffsll(km) - 1) : -1;
                if (km) km &= km - 1;
            }
            u64 v0[8], v1[8];
            #pragma unroll
            for (int j = 0; j < 8; ++j) {
                v0[j] = 0ull; v1[j] = 0ull;
                if (bs[j] >= 0) {
                    const u64* row = mat + (size_t)(c * 64 + bs[j]) * NWORDS;
                    if (lane > c) v0[j] = row[lane];
                    if (lane + 64 < NWORDS && lane + 64 > c) v1[j] = row[lane + 64];
                }
            }
            #pragma unroll
            for (int j = 0; j < 8; ++j) { f0 |= v0[j]; f1 |= v1[j]; }
        }
        r0 |= f0; r1 |= f1;
    }

    __syncthreads();
    for (int r = lane; r < POSTN; r += 64) {
        float4 b = make_float4(0.f, 0.f, 0.f, 0.f);
        if (r < cnt) b = tb[kept[r]];
        float* o = out + r * 5;
        o[0] = 0.f; o[1] = b.x; o[2] = b.y; o[3] = b.z; o[4] = b.w;
    }
}

// ---------------- host launcher ----------------
extern "C" void kernel_launch(void* const* d_in, const int* in_sizes, int n_in,
                              void* d_out, int out_size, void* d_ws, size_t ws_size,
                              hipStream_t stream) {
    const float* scores = (const float*)d_in[0];
    const float* deltas = (const float*)d_in[1];
    const float* iminfo = (const float*)d_in[2];
    float* out = (float*)d_out;

    char* ws = (char*)d_ws;
    // workspace layout (16B-aligned), total 9,102,400 bytes
    float4*             boxesj = (float4*)(ws + 0);                       // 221184*16 = 3538944
    unsigned int*       keys   = (unsigned int*)(ws + 3538944);           // 221184*4  = 884736
    unsigned int*       hist   = (unsigned int*)(ws + 4423680);           // 2*256*4 used (4096 reserved)
    unsigned int*       state  = (unsigned int*)(ws + 4427776);           // 64
    u64*                cand   = (u64*)(ws + 4427840);                    // 8192*8    = 65536
    float4*             tb     = (float4*)(ws + 4493376);                 // 6016*16   = 96256
    u64*                vmask  = (u64*)(ws + 4589632);                    // 768
    u64*                mat    = (u64*)(ws + 4590400);                    // 6000*94*8 = 4512000
    unsigned int*       rankp  = (unsigned int*)mat;                      // aliases mat head (32KB),
                                                                          // consumed before mat written

    const int NB = N_ANCH / 256;   // 864 exactly

    init_kernel<<<49, 256, 0, stream>>>((float4*)(ws + 4423680), (float4*)mat);
    decode_kernel<<<NB, 256, 0, stream>>>(scores, deltas, iminfo, boxesj, keys, hist + 256);
    select_kernel<<<1, 256, 0, stream>>>(hist + 256, state, 24);
    hist_kernel<<<NB, 256, 0, stream>>>(keys, state, hist, 16, 0xFF000000u);
    select_kernel<<<1, 256, 0, stream>>>(hist, state, 16);
    compact_kernel<<<NB, 256, 0, stream>>>(keys, state, cand);
    rank_kernel<<<dim3(CAND_CAP / 256, CAND_CAP / RJ), 256, 0, stream>>>(cand, rankp);
    scatter_kernel<<<CAND_CAP / 256, 256, 0, stream>>>(cand, rankp, boxesj, tb, vmask);
    nms_matrix_kernel<<<dim3(NWORDS, NWORDS), 64, 0, stream>>>(tb, mat);
    nms_scan_kernel<<<1, 64, 0, stream>>>(mat, vmask, tb, out);
}